// Round 7
// baseline (723.126 us; speedup 1.0000x reference)
//
#include <hip/hip_runtime.h>
#include <hip/hip_bf16.h>
#include <hip/hip_fp16.h>

#define N_NODES 20000
#define HID 64
#define EPS 1e-5f

typedef _Float16 half8 __attribute__((ext_vector_type(8)));
typedef float f32x4 __attribute__((ext_vector_type(4)));

// Per-graph pointer set (passed by value; attention uses parity split so each
// XCD only touches one graph's gather array).
struct GP {
    const int* ei;      // [2, E]
    const int* batch;   // [N] sorted
    const float* x;     // [N, 5]
    int* deg;           // rowptr after scan, N+1
    int* cursor;
    int* csr;           // E + N entries; values are BYTE offsets (src*128)
    float* h;           // [N, 64]
    __half* xlh;        // [N, 64] fp16 gather array (source transform)
    float* xr;          // [N, 64] target transform
    float* gb;          // attention output (pre-BN)
    float* stats;       // 8 layers * 128 (sum, sumsq)
    float* osum;        // 32 * 64 pooled sums
};

// ---------------- CSR build (both graphs in one dispatch) ----------------

__global__ void k_csr_init(GP a, GP b, int n, int two) {
    int t = blockIdx.x * blockDim.x + threadIdx.x;
    if (t < n) {
        a.deg[t] = 1;  // self-loop
        if (two) b.deg[t] = 1;
    }
}

__global__ void k_count(GP a, GP b, int Ea, int Eb, int two) {
    int t = blockIdx.x * blockDim.x + threadIdx.x;
    if (t < Ea) atomicAdd(&a.deg[a.ei[Ea + t]], 1);
    if (two && t < Eb) atomicAdd(&b.deg[b.ei[Eb + t]], 1);
}

#define SCAN_T 1024
#define SCAN_C 20
__global__ __launch_bounds__(1024) void k_scan(GP a, GP b, int n, int totA, int totB) {
    GP g = blockIdx.x ? b : a;
    int total = blockIdx.x ? totB : totA;
    __shared__ int sd[SCAN_T];
    int t = threadIdx.x;
    int base = t * SCAN_C;
    int loc[SCAN_C];
    int s = 0;
#pragma unroll
    for (int i = 0; i < SCAN_C; ++i) {
        int idx = base + i;
        loc[i] = (idx < n) ? g.deg[idx] : 0;
        s += loc[i];
    }
    sd[t] = s;
    __syncthreads();
    for (int off = 1; off < SCAN_T; off <<= 1) {
        int v = (t >= off) ? sd[t - off] : 0;
        __syncthreads();
        sd[t] += v;
        __syncthreads();
    }
    int run = sd[t] - s;  // exclusive prefix
#pragma unroll
    for (int i = 0; i < SCAN_C; ++i) {
        int idx = base + i;
        if (idx < n) { g.deg[idx] = run; g.cursor[idx] = run; run += loc[i]; }
    }
    if (t == 0) g.deg[n] = total;
}

// csr values are byte offsets: src * 128 (row stride of fp16 xl)
__global__ void k_scatter(GP a, GP b, int Ea, int Eb, int n, int two) {
    int t = blockIdx.x * blockDim.x + threadIdx.x;
    if (t < Ea) {
        int s = a.ei[t], d = a.ei[Ea + t];
        a.csr[atomicAdd(&a.cursor[d], 1)] = s * 128;
    } else if (t < Ea + n) {
        int nn = t - Ea;
        a.csr[atomicAdd(&a.cursor[nn], 1)] = nn * 128;
    }
    if (two) {
        if (t < Eb) {
            int s = b.ei[t], d = b.ei[Eb + t];
            b.csr[atomicAdd(&b.cursor[d], 1)] = s * 128;
        } else if (t < Eb + n) {
            int nn = t - Eb;
            b.csr[atomicAdd(&b.cursor[nn], 1)] = nn * 128;
        }
    }
}

// ---------------- node linear: h = x @ Wn + b ----------------

__global__ void k_nodelin(GP a, GP b, int nPer, const float* __restrict__ Wn,
                          const float* __restrict__ bn, int n) {
    int bid = blockIdx.x;
    GP g = a;
    if (bid >= nPer) { g = b; bid -= nPer; }
    int idx = bid * 256 + threadIdx.x;
    if (idx >= n * HID) return;
    int node = idx >> 6, c = idx & 63;
    float acc = bn[c];
#pragma unroll
    for (int k = 0; k < 5; ++k) acc += g.x[node * 5 + k] * Wn[k * HID + c];
    g.h[idx] = acc;
}

// ---------------- dual linear via MFMA, fused with prev BN+ELU+residual ------
// 64-node tile per block. Phase 1: h_new = h + elu(BN(gb)) elementwise, written
// to global fp32 and to an LDS fp16 tile (row stride 72 = bank-pad + 16B align).
// Phase 2: D = hT @ [Wl|Wr] via mfma_f32_16x16x32_f16, layouts:
//   A[m=lane&15][k=quad*8+j], B[k=quad*8+j][n=lane&15], C col=lane&15 row=quad*4+reg.

__global__ __launch_bounds__(256) void k_lin2(GP ga, GP gbp, int nPer, int n,
        const float* __restrict__ Wl, const float* __restrict__ bl,
        const float* __restrict__ Wr, const float* __restrict__ br,
        const float* __restrict__ gamma, const float* __restrict__ beta, int layer) {
    __shared__ _Float16 wT[128 * 72];  // [channel c(0..127 = Wl|Wr)][k], stride 72
    __shared__ _Float16 hT[64 * 72];   // [node-in-tile][k], stride 72
    int bid = blockIdx.x;
    GP g = ga;
    if (bid >= nPer) { g = gbp; bid -= nPer; }
    int tid = threadIdx.x;
    int lane = tid & 63;
    int w = tid >> 6;           // wave id 0..3 -> node row-group
    int quad = lane >> 4;
    int m = lane & 15;

    // stage transposed fp16 weights (coalesced global reads)
    for (int i = tid; i < 4096; i += 256) {
        int k = i >> 6, c = i & 63;
        wT[c * 72 + k] = (_Float16)Wl[i];
        wT[(c + 64) * 72 + k] = (_Float16)Wr[i];
    }

    // phase 1: BN+ELU+residual for this block's 64 nodes
    int base = bid * 64;
    {
        float mu = 0.f, inv = 1.f, gam = 1.f, bet = 0.f;
        if (layer > 0) {
            const float* st = g.stats + (layer - 1) * 128;
            float invn = 1.0f / (float)n;
            mu = st[lane] * invn;
            float var = st[64 + lane] * invn - mu * mu;
            inv = rsqrtf(fmaxf(var, 0.f) + EPS);
            gam = gamma[lane]; bet = beta[lane];
        }
#pragma unroll
        for (int it = 0; it < 16; ++it) {
            int rr = it * 4 + w;
            int node = base + rr;
            float hv = 0.f;
            if (node < n) {
                size_t off = (size_t)node * 64 + lane;
                if (layer > 0) {
                    float gv = g.gb[off];
                    float ov = g.h[off];
                    float v = (gv - mu) * inv * gam + bet;
                    v = v > 0.f ? v : expm1f(v);
                    hv = ov + v;
                    g.h[off] = hv;
                } else {
                    hv = g.h[off];
                }
            }
            hT[rr * 72 + lane] = (_Float16)hv;
        }
    }
    __syncthreads();

    // phase 2: MFMA. wave w handles nodes base+w*16..+15, all 8 column groups.
    half8 a0 = *(const half8*)&hT[(w * 16 + m) * 72 + quad * 8];
    half8 a1 = *(const half8*)&hT[(w * 16 + m) * 72 + 32 + quad * 8];
#pragma unroll
    for (int cg = 0; cg < 8; ++cg) {
        half8 b0 = *(const half8*)&wT[(cg * 16 + m) * 72 + quad * 8];
        half8 b1 = *(const half8*)&wT[(cg * 16 + m) * 72 + 32 + quad * 8];
        f32x4 acc = {0.f, 0.f, 0.f, 0.f};
        acc = __builtin_amdgcn_mfma_f32_16x16x32_f16(a0, b0, acc, 0, 0, 0);
        acc = __builtin_amdgcn_mfma_f32_16x16x32_f16(a1, b1, acc, 0, 0, 0);
        float bias = (cg < 4) ? bl[cg * 16 + m] : br[(cg - 4) * 16 + m];
#pragma unroll
        for (int reg = 0; reg < 4; ++reg) {
            int node = base + w * 16 + quad * 4 + reg;
            if (node < n) {
                float v = acc[reg] + bias;
                if (cg < 4) g.xlh[(size_t)node * 64 + cg * 16 + m] = __float2half(v);
                else        g.xr[(size_t)node * 64 + (cg - 4) * 16 + m] = v;
            }
        }
    }
}

// ---------------- attention: self-score-stabilized softmax + BN stats ----------
// Parity split: graph = blockIdx&1 (XCD locality). csr holds byte offsets;
// att prescaled by log2(e) so weights come straight from exp2f.

__device__ __forceinline__ float red16(float p) {
    p += __int_as_float(__builtin_amdgcn_update_dpp(0, __float_as_int(p), 0xB1, 0xF, 0xF, true));  // xor 1
    p += __int_as_float(__builtin_amdgcn_update_dpp(0, __float_as_int(p), 0x4E, 0xF, 0xF, true));  // xor 2
    p += __int_as_float(__builtin_amdgcn_update_dpp(0, __float_as_int(p), 0x141, 0xF, 0xF, true)); // row_half_mirror
    p += __int_as_float(__builtin_amdgcn_update_dpp(0, __float_as_int(p), 0x140, 0xF, 0xF, true)); // row_mirror
    return p;
}

__global__ __launch_bounds__(1024) void k_attn(GP ga, GP gbp, int nPer,
        const float* __restrict__ att, const float* __restrict__ cbias, int layer, int n) {
    int bid = blockIdx.x;
    GP g = (bid & 1) ? gbp : ga;   // parity -> XCD partitioning
    bid >>= 1;
    int lane = threadIdx.x & 63;
    int wid = threadIdx.x >> 6;
    int gw = bid * 16 + wid;
    int nw = nPer * 16;
    float attv = att[lane] * 1.44269504f;   // log2(e) prescale: exp -> exp2
    float attv2 = attv * 0.2f;
    float cb = cbias[lane];
    const int* __restrict__ rowptr = g.deg;
    const int* __restrict__ csr = g.csr;
    const char* xlb = (const char*)g.xlh + (size_t)lane * 2;  // lane-fixed base
    const float* __restrict__ xr = g.xr;
    float* __restrict__ gbuf = g.gb;
    float* st = g.stats + layer * 128;
    float bsum = 0.f, bsq = 0.f;
    for (int node = gw; node < n; node += nw) {
        int start = rowptr[node], end = rowptr[node + 1];
        float xrv = xr[(size_t)node * 64 + lane];
        // self-loop score as softmax stabilizer (exact: softmax shift-invariant)
        float xself = __half2float(*(const __half*)(xlb + (size_t)node * 128));
        float ts = xself + xrv;
        float sself = red16(ts * (ts > 0.f ? attv : attv2));
        float lsum = 0.f, acc = 0.f;
        int idx = start;
        for (; idx + 8 <= end; idx += 8) {
            int off[8];
            float xv[8];
#pragma unroll
            for (int j = 0; j < 8; ++j) off[j] = csr[idx + j];
#pragma unroll
            for (int j = 0; j < 8; ++j) xv[j] = __half2float(*(const __half*)(xlb + off[j]));
#pragma unroll
            for (int j = 0; j < 8; ++j) {
                float t = xv[j] + xrv;
                float p = red16(t * (t > 0.f ? attv : attv2));
                float w = exp2f(fminf(p - sself, 110.f));
                lsum += w;
                acc = fmaf(w, xv[j], acc);
            }
        }
        for (; idx + 4 <= end; idx += 4) {
            int off[4];
            float xv[4];
#pragma unroll
            for (int j = 0; j < 4; ++j) off[j] = csr[idx + j];
#pragma unroll
            for (int j = 0; j < 4; ++j) xv[j] = __half2float(*(const __half*)(xlb + off[j]));
#pragma unroll
            for (int j = 0; j < 4; ++j) {
                float t = xv[j] + xrv;
                float p = red16(t * (t > 0.f ? attv : attv2));
                float w = exp2f(fminf(p - sself, 110.f));
                lsum += w;
                acc = fmaf(w, xv[j], acc);
            }
        }
        for (; idx < end; ++idx) {
            int o = csr[idx];
            float x0 = __half2float(*(const __half*)(xlb + o));
            float t0 = x0 + xrv;
            float p0 = red16(t0 * (t0 > 0.f ? attv : attv2));
            float w0 = exp2f(fminf(p0 - sself, 110.f));
            lsum += w0;
            acc = fmaf(w0, x0, acc);
        }
        float outv = acc / lsum + cb;
        gbuf[(size_t)node * 64 + lane] = outv;
        bsum += outv; bsq += outv * outv;
    }
    __shared__ float sred[1024];
    sred[threadIdx.x] = bsum;
    __syncthreads();
    if (threadIdx.x < 64) {
        float t = 0.f;
#pragma unroll
        for (int w = 0; w < 16; ++w) t += sred[w * 64 + threadIdx.x];
        atomicAdd(&st[threadIdx.x], t);
    }
    __syncthreads();
    sred[threadIdx.x] = bsq;
    __syncthreads();
    if (threadIdx.x < 64) {
        float t = 0.f;
#pragma unroll
        for (int w = 0; w < 16; ++w) t += sred[w * 64 + threadIdx.x];
        atomicAdd(&st[64 + threadIdx.x], t);
    }
}

// ---------------- pool, fused with layer-7 BN+ELU+residual ----------------

__global__ __launch_bounds__(256) void k_pool(GP ga, GP gbp, int nPer,
        const float* __restrict__ gamma, const float* __restrict__ beta, int n) {
    int bid = blockIdx.x;
    GP g = ga;
    if (bid >= nPer) { g = gbp; bid -= nPer; }
    int lane = threadIdx.x & 63, w = threadIdx.x >> 6;
    const float* st = g.stats + 7 * 128;
    float invn = 1.f / (float)n;
    float mu = st[lane] * invn;
    float var = st[64 + lane] * invn - mu * mu;
    float inv = rsqrtf(fmaxf(var, 0.f) + EPS);
    float gam = gamma[lane], bet = beta[lane];
    int chunk = (n + nPer - 1) / nPer;
    int s = bid * chunk;
    int e = min(s + chunk, n);
    float acc = 0.f;
    int cur = -1;
    for (int node = s + w; node < e; node += 4) {
        int bg = g.batch[node];  // wave-uniform
        size_t off = (size_t)node * 64 + lane;
        float gv = g.gb[off];
        float hv = g.h[off];
        float v = (gv - mu) * inv * gam + bet;
        float hn = hv + (v > 0.f ? v : expm1f(v));
        if (bg != cur) {
            if (cur >= 0) atomicAdd(&g.osum[cur * 64 + lane], acc);
            acc = 0.f; cur = bg;
        }
        acc += hn;
    }
    if (cur >= 0) atomicAdd(&g.osum[cur * 64 + lane], acc);
}

// ---------------- FC head (divides pooled sums by counts) ----------------

__device__ __forceinline__ int lb(const int* __restrict__ b, int n, int v) {
    int lo = 0, hi = n;
    while (lo < hi) { int mid = (lo + hi) >> 1; if (b[mid] < v) lo = mid + 1; else hi = mid; }
    return lo;
}

__global__ __launch_bounds__(256) void k_fc(const float* __restrict__ o1, const float* __restrict__ o2,
                                            const int* __restrict__ b1, const int* __restrict__ b2,
                                            const float* __restrict__ f1w, const float* __restrict__ f1b,
                                            const float* __restrict__ f2w, const float* __restrict__ f2b,
                                            const float* __restrict__ f3w, const float* __restrict__ f3b,
                                            float* __restrict__ out, int n) {
    int gid = blockIdx.x, t = threadIdx.x;
    __shared__ float cin[128];
    __shared__ float h1[256];
    __shared__ float red[128];
    __shared__ int cnts[2];
    if (t == 0) cnts[0] = lb(b1, n, gid + 1) - lb(b1, n, gid);
    if (t == 1) cnts[1] = lb(b2, n, gid + 1) - lb(b2, n, gid);
    __syncthreads();
    if (t < 64) {
        float c1 = (float)(cnts[0] > 0 ? cnts[0] : 1);
        float c2 = (float)(cnts[1] > 0 ? cnts[1] : 1);
        cin[t] = o1[gid * 64 + t] / c1;
        cin[64 + t] = o2[gid * 64 + t] / c2;
    }
    __syncthreads();
    float a = f1b[t];
#pragma unroll 8
    for (int k = 0; k < 128; ++k) a += cin[k] * f1w[k * 256 + t];
    h1[t] = fmaxf(a, 0.f);
    __syncthreads();
    if (t < 128) {
        float a2 = f2b[t];
#pragma unroll 8
        for (int k = 0; k < 256; ++k) a2 += h1[k] * f2w[k * 128 + t];
        red[t] = fmaxf(a2, 0.f) * f3w[t];
    }
    __syncthreads();
    for (int off = 64; off > 0; off >>= 1) {
        if (t < off) red[t] += red[t + off];
        __syncthreads();
    }
    if (t == 0) out[gid] = red[0] + f3b[0];
}

// ---------------- host ----------------

extern "C" void kernel_launch(void* const* d_in, const int* in_sizes, int n_in,
                              void* d_out, int out_size, void* d_ws, size_t ws_size,
                              hipStream_t stream) {
    const float* x1 = (const float*)d_in[0];
    const float* x2 = (const float*)d_in[1];
    const int* ei1 = (const int*)d_in[2];
    const int* ei2 = (const int*)d_in[3];
    const int* b1 = (const int*)d_in[4];
    const int* b2 = (const int*)d_in[5];
    const float* Wn = (const float*)d_in[6];
    const float* bnode = (const float*)d_in[7];
    const float* Wl = (const float*)d_in[8];
    const float* bl = (const float*)d_in[9];
    const float* Wr = (const float*)d_in[10];
    const float* br = (const float*)d_in[11];
    const float* att = (const float*)d_in[12];
    const float* cbias = (const float*)d_in[13];
    const float* gamma = (const float*)d_in[14];
    const float* beta = (const float*)d_in[15];
    const float* f1w = (const float*)d_in[16];
    const float* f1b = (const float*)d_in[17];
    const float* f2w = (const float*)d_in[18];
    const float* f2b = (const float*)d_in[19];
    const float* f3w = (const float*)d_in[20];
    const float* f3b = (const float*)d_in[21];
    float* out = (float*)d_out;

    const int N = N_NODES;
    const int EA = in_sizes[2] / 2;
    const int EB = in_sizes[3] / 2;
    const size_t INT_PG = 20096 + 20096 + 340096;  // deg, cursor, csr
    const size_t BIG = (size_t)N * 64;             // float-sized slot
    const size_t SMALL = 2 * 1024 + 2 * 2048;      // stats + osum
    const size_t dualBytes = 2 * INT_PG * 4 + (8 * BIG + SMALL) * 4;
    const int dual = (ws_size >= dualBytes) ? 1 : 0;

    int* ibase = (int*)d_ws;
    int* iA = ibase;
    int* iB = dual ? ibase + INT_PG : ibase;
    float* fbase = (float*)(ibase + (size_t)(dual ? 2 : 1) * INT_PG);
    float* hA = fbase;
    float* xlA = hA + BIG;      // holds fp16 xl (uses half the slot)
    float* xrA = xlA + BIG;
    float* gbA = xrA + BIG;
    float* hB = dual ? gbA + BIG : hA;
    float* xlB = dual ? hB + BIG : xlA;
    float* xrB = dual ? xlB + BIG : xrA;
    float* gbB = dual ? xrB + BIG : gbA;
    float* small = dual ? gbB + BIG : gbA + BIG;
    float* statsA = small;
    float* statsB = small + 1024;
    float* osumA = small + 2048;
    float* osumB = small + 4096;

    GP A, B;
    A.ei = ei1; A.batch = b1; A.x = x1;
    A.deg = iA; A.cursor = iA + 20096; A.csr = iA + 40192;
    A.h = hA; A.xlh = (__half*)xlA; A.xr = xrA; A.gb = gbA; A.stats = statsA; A.osum = osumA;
    B.ei = ei2; B.batch = b2; B.x = x2;
    B.deg = iB; B.cursor = iB + 20096; B.csr = iB + 40192;
    B.h = hB; B.xlh = (__half*)xlB; B.xr = xrB; B.gb = gbB; B.stats = statsB; B.osum = osumB;

    hipMemsetAsync(small, 0, SMALL * sizeof(float), stream);

    const int LIN2_NB = (N + 63) / 64;  // 313 blocks per graph, 64-node tiles
    const int ATT_NB = 256;             // per graph, 1024-thread blocks, parity split
    const int POOL_NB = 250;            // per graph

    if (dual) {
        int Emax = EA > EB ? EA : EB;
        k_csr_init<<<(N + 255) / 256, 256, 0, stream>>>(A, B, N, 1);
        k_count<<<(Emax + 255) / 256, 256, 0, stream>>>(A, B, EA, EB, 1);
        k_scan<<<2, 1024, 0, stream>>>(A, B, N, EA + N, EB + N);
        k_scatter<<<(Emax + N + 255) / 256, 256, 0, stream>>>(A, B, EA, EB, N, 1);
        k_nodelin<<<2 * ((N * 64) / 256), 256, 0, stream>>>(A, B, (N * 64) / 256, Wn, bnode, N);
        for (int l = 0; l < 8; ++l) {
            const float* gm = l ? gamma + (l - 1) * 64 : gamma;
            const float* bt = l ? beta + (l - 1) * 64 : beta;
            k_lin2<<<2 * LIN2_NB, 256, 0, stream>>>(A, B, LIN2_NB, N, Wl + l * 4096, bl + l * 64,
                                                    Wr + l * 4096, br + l * 64, gm, bt, l);
            k_attn<<<2 * ATT_NB, 1024, 0, stream>>>(A, B, ATT_NB, att + l * 64, cbias + l * 64, l, N);
        }
        k_pool<<<2 * POOL_NB, 256, 0, stream>>>(A, B, POOL_NB, gamma + 7 * 64, beta + 7 * 64, N);
    } else {
        for (int gi = 0; gi < 2; ++gi) {
            GP G = gi ? B : A;
            int E = gi ? EB : EA;
            k_csr_init<<<(N + 255) / 256, 256, 0, stream>>>(G, G, N, 0);
            k_count<<<(E + 255) / 256, 256, 0, stream>>>(G, G, E, E, 0);
            k_scan<<<1, 1024, 0, stream>>>(G, G, N, E + N, E + N);
            k_scatter<<<(E + N + 255) / 256, 256, 0, stream>>>(G, G, E, E, N, 0);
            k_nodelin<<<(N * 64) / 256, 256, 0, stream>>>(G, G, (N * 64) / 256, Wn, bnode, N);
            for (int l = 0; l < 8; ++l) {
                const float* gm = l ? gamma + (l - 1) * 64 : gamma;
                const float* bt = l ? beta + (l - 1) * 64 : beta;
                k_lin2<<<LIN2_NB, 256, 0, stream>>>(G, G, LIN2_NB, N, Wl + l * 4096, bl + l * 64,
                                                    Wr + l * 4096, br + l * 64, gm, bt, l);
                k_attn<<<2 * ATT_NB, 1024, 0, stream>>>(G, G, ATT_NB, att + l * 64, cbias + l * 64, l, N);
            }
            k_pool<<<POOL_NB, 256, 0, stream>>>(G, G, POOL_NB, gamma + 7 * 64, beta + 7 * 64, N);
        }
    }
    k_fc<<<32, 256, 0, stream>>>(osumA, osumB, b1, b2, f1w, f1b, f2w, f2b, f3w, f3b, out, N);
}